// Round 2
// baseline (682.206 us; speedup 1.0000x reference)
//
#include <hip/hip_runtime.h>
#include <math.h>

#define DEV __device__ __forceinline__

typedef short v2s __attribute__((ext_vector_type(2)));

// ---- ws layout (word-indexed, total ~9.2 KB; round-1 proved ws >= 17.7KB works) ----
// [0..3]   : reduction slots (bit-patterns of non-negative floats)
// scales (float): W1S..  weights (packed short2-in-int): W1Q..
static constexpr int W1S = 16;        // 64
static constexpr int W2S = 80;        // 32
static constexpr int W3S = 112;       // 32
static constexpr int W4S = 144;       // 5
static constexpr int W1Q = 160;       // 64 rows x 8  ints
static constexpr int W2Q = 672;       // 32 rows x 32 ints
static constexpr int W3Q = 1696;      // 32 rows x 16 ints
static constexpr int W4Q = 2208;      // 5  rows x 16 ints

DEV int imin(int a, int b) { return a < b ? a : b; }
DEV int imax(int a, int b) { return a > b ? a : b; }

DEV int dot2(int a, int b, int c) {
#if defined(__has_builtin) && __has_builtin(__builtin_amdgcn_sdot2)
    union U { int i; v2s s; };
    U ua; ua.i = a; U ub; ub.i = b;
    return __builtin_amdgcn_sdot2(ua.s, ub.s, c, false);
#else
    return c + (int)(short)(a & 0xFFFF) * (int)(short)(b & 0xFFFF)
             + (int)(short)((unsigned)a >> 16) * (int)(short)((unsigned)b >> 16);
#endif
}

DEV int qbias_i(float b, float bs) {
    float q = rintf(b / bs);
    q = fminf(fmaxf(q, -2.1474835e9f), 2.1474835e9f);
    return (int)q;
}

DEV void reduceAndAtomicMax(float v, unsigned int* slot) {
    #pragma unroll
    for (int off = 32; off; off >>= 1) v = fmaxf(v, __shfl_xor(v, off));
    __shared__ float sm[4];
    const int wid = threadIdx.x >> 6;
    if ((threadIdx.x & 63) == 0) sm[wid] = v;
    __syncthreads();
    if (threadIdx.x == 0) {
        float m = fmaxf(fmaxf(sm[0], sm[1]), fmaxf(sm[2], sm[3]));
        atomicMax(slot, __float_as_uint(m)); // non-negative floats: bit-order == value-order
    }
}

// ---- setup: quantize + pack weights into ws; zero the 4 reduction slots ----
__global__ __launch_bounds__(256) void k_quantw(const float* __restrict__ W1,
                                                const float* __restrict__ W2,
                                                const float* __restrict__ W3,
                                                const float* __restrict__ W4,
                                                float* __restrict__ wsf) {
    int* wsi = (int*)wsf;
    const int t = threadIdx.x;
    if (t >= 192 && t < 196) ((unsigned int*)wsf)[t - 192] = 0u;

    const float* W = nullptr; int row = -1, cols = 0; int* dq = nullptr; float* dsc = nullptr;
    if (t < 64)       { W = W1; row = t;       cols = 16; dq = wsi + W1Q + row * 8;  dsc = wsf + W1S + row; }
    else if (t < 96)  { W = W2; row = t - 64;  cols = 64; dq = wsi + W2Q + row * 32; dsc = wsf + W2S + row; }
    else if (t < 128) { W = W3; row = t - 96;  cols = 32; dq = wsi + W3Q + row * 16; dsc = wsf + W3S + row; }
    else if (t < 133) { W = W4; row = t - 128; cols = 32; dq = wsi + W4Q + row * 16; dsc = wsf + W4S + row; }
    if (row >= 0) {
        const float* src = W + row * cols;
        float m = 0.f;
        for (int i = 0; i < cols; i++) m = fmaxf(m, fabsf(src[i]));
        float s = fmaxf(m * (1.0f / 127.0f), 1e-8f);
        *dsc = s;
        for (int i = 0; i < cols; i += 2) {
            int q0 = imax(imin((int)rintf(src[i]     / s), 127), -128);
            int q1 = imax(imin((int)rintf(src[i + 1] / s), 127), -128);
            dq[i / 2] = (q0 & 0xFFFF) | (q1 << 16);
        }
    }
}

// ---- K0: max|x| ----
__global__ __launch_bounds__(256) void k_absmax(const float4* __restrict__ x,
                                                unsigned int* __restrict__ slots, int n4) {
    float m = 0.f;
    for (int i = blockIdx.x * blockDim.x + threadIdx.x; i < n4; i += gridDim.x * blockDim.x) {
        float4 v = x[i];
        m = fmaxf(m, fmaxf(fmaxf(fabsf(v.x), fabsf(v.y)), fmaxf(fabsf(v.z), fabsf(v.w))));
    }
    reduceAndAtomicMax(m, slots + 0);
}

// ---- integer linear layer via v_dot2_i32_i16: in packed short2, weights packed short2 ----
// out[o] = float( dot(in,W[o]) + b_int[o] ) * bias_scale[o]   (+relu)
template <int IN, int OUT, bool RELU>
DEV void layer_i(const int* __restrict__ wq, const int2* __restrict__ bias,
                 const int* in, float* outv) {
    #pragma unroll
    for (int o = 0; o < OUT; o++) {
        const int* wr = wq + o * (IN / 2);
        int a0 = 0, a1 = 0;
        #pragma unroll
        for (int i = 0; i < IN / 2; i += 2) {
            a0 = dot2(in[i],     wr[i],     a0);
            a1 = dot2(in[i + 1], wr[i + 1], a1);
        }
        int2 bb = bias[o];
        float v = (float)(a0 + a1 + bb.x) * __int_as_float(bb.y);
        outv[o] = RELU ? fmaxf(v, 0.f) : v;
    }
}

template <int N> // h >= 0 (post-relu), quantize + pack into short2-in-int
DEV void quant_pack(const float* h, float inv, int* hp) {
    #pragma unroll
    for (int i = 0; i < N; i += 2) {
        int q0 = imin((int)rintf(h[i]     * inv), 32767);
        int q1 = imin((int)rintf(h[i + 1] * inv), 32767);
        hp[i / 2] = (q0 & 0xFFFF) | (q1 << 16);
    }
}

template <int N>
DEV float maxarr(const float* h) {
    float m = 0.f;
    #pragma unroll
    for (int i = 0; i < N; i++) m = fmaxf(m, h[i]);
    return m;
}

// ---- staged forward: recompute through layer STAGE; stages 1..3 reduce max, stage 4 writes out ----
template <int STAGE>
__global__ __launch_bounds__(256) void k_stage(const float* __restrict__ x,
                                               const float* __restrict__ b1,
                                               const float* __restrict__ b2,
                                               const float* __restrict__ b3,
                                               const float* __restrict__ b4,
                                               const float* __restrict__ wsf,
                                               unsigned int* __restrict__ slots,
                                               float* __restrict__ out) {
    const int* wsi = (const int*)wsf;
    __shared__ int2 B1[64], B2[32], B3[32], B4[8];
    const int t = threadIdx.x;

    const float s0 = fmaxf(__uint_as_float(slots[0]) * (1.f / 32767.f), 1e-8f);
    float s1 = 1.f, s2 = 1.f, s3 = 1.f;
    if (STAGE >= 2) s1 = fmaxf(__uint_as_float(slots[1]) * (1.f / 32767.f), 1e-8f);
    if (STAGE >= 3) s2 = fmaxf(__uint_as_float(slots[2]) * (1.f / 32767.f), 1e-8f);
    if (STAGE >= 4) s3 = fmaxf(__uint_as_float(slots[3]) * (1.f / 32767.f), 1e-8f);

    if (t < 64) { float bs = wsf[W1S + t] * s0; B1[t] = make_int2(qbias_i(b1[t], bs), __float_as_int(bs)); }
    if (STAGE >= 2 && t < 32) { float bs = wsf[W2S + t] * s1; B2[t] = make_int2(qbias_i(b2[t], bs), __float_as_int(bs)); }
    if (STAGE >= 3 && t < 32) { float bs = wsf[W3S + t] * s2; B3[t] = make_int2(qbias_i(b3[t], bs), __float_as_int(bs)); }
    if (STAGE >= 4 && t < 5)  { float bs = wsf[W4S + t] * s3; B4[t] = make_int2(qbias_i(b4[t], bs), __float_as_int(bs)); }
    __syncthreads();

    const size_t row = (size_t)blockIdx.x * 256 + t;

    // quantize + pack input row (16 elems -> 8 ints)
    int xp[8];
    {
        const float4* xr = (const float4*)(x + row * 16);
        const float inv0 = 1.f / s0;
        #pragma unroll
        for (int c = 0; c < 4; c++) {
            float4 v = xr[c];
            int q0 = imax(imin((int)rintf(v.x * inv0), 32767), -32768);
            int q1 = imax(imin((int)rintf(v.y * inv0), 32767), -32768);
            int q2 = imax(imin((int)rintf(v.z * inv0), 32767), -32768);
            int q3 = imax(imin((int)rintf(v.w * inv0), 32767), -32768);
            xp[2 * c + 0] = (q0 & 0xFFFF) | (q1 << 16);
            xp[2 * c + 1] = (q2 & 0xFFFF) | (q3 << 16);
        }
    }

    float h1[64];
    layer_i<16, 64, true>(wsi + W1Q, B1, xp, h1);
    if (STAGE == 1) { reduceAndAtomicMax(maxarr<64>(h1), slots + 1); return; }
    int h1p[32];
    quant_pack<64>(h1, 1.f / s1, h1p);

    float h2[32];
    layer_i<64, 32, true>(wsi + W2Q, B2, h1p, h2);
    if (STAGE == 2) { reduceAndAtomicMax(maxarr<32>(h2), slots + 2); return; }
    int h2p[16];
    quant_pack<32>(h2, 1.f / s2, h2p);

    float h3[32];
    layer_i<32, 32, true>(wsi + W3Q, B3, h2p, h3);
    if (STAGE == 3) { reduceAndAtomicMax(maxarr<32>(h3), slots + 3); return; }
    int h3p[16];
    quant_pack<32>(h3, 1.f / s3, h3p);

    float lg[5];
    layer_i<32, 5, false>(wsi + W4Q, B4, h3p, lg);

    // softmax over 5
    float m = lg[0];
    #pragma unroll
    for (int i = 1; i < 5; i++) m = fmaxf(m, lg[i]);
    float e[5], ssum = 0.f;
    #pragma unroll
    for (int i = 0; i < 5; i++) { e[i] = expf(lg[i] - m); ssum += e[i]; }
    const float r = 1.f / ssum;
    #pragma unroll
    for (int i = 0; i < 5; i++) out[row * 5 + i] = e[i] * r;
}

extern "C" void kernel_launch(void* const* d_in, const int* in_sizes, int n_in,
                              void* d_out, int out_size, void* d_ws, size_t ws_size,
                              hipStream_t stream) {
    const float* x  = (const float*)d_in[0];
    const float* W1 = (const float*)d_in[1];
    const float* b1 = (const float*)d_in[2];
    const float* W2 = (const float*)d_in[3];
    const float* b2 = (const float*)d_in[4];
    const float* W3 = (const float*)d_in[5];
    const float* b3 = (const float*)d_in[6];
    const float* W4 = (const float*)d_in[7];
    const float* b4 = (const float*)d_in[8];
    float* out = (float*)d_out;
    float* ws = (float*)d_ws;
    unsigned int* slots = (unsigned int*)d_ws;

    const int B = in_sizes[0] / 16;      // 1 << 20
    const int blocks = (B + 255) / 256;  // 4096

    k_quantw<<<1, 256, 0, stream>>>(W1, W2, W3, W4, ws);
    k_absmax<<<2048, 256, 0, stream>>>((const float4*)x, slots, (in_sizes[0] + 3) / 4);
    k_stage<1><<<blocks, 256, 0, stream>>>(x, b1, b2, b3, b4, ws, slots, out);
    k_stage<2><<<blocks, 256, 0, stream>>>(x, b1, b2, b3, b4, ws, slots, out);
    k_stage<3><<<blocks, 256, 0, stream>>>(x, b1, b2, b3, b4, ws, slots, out);
    k_stage<4><<<blocks, 256, 0, stream>>>(x, b1, b2, b3, b4, ws, slots, out);
}